// Round 7
// baseline (132.520 us; speedup 1.0000x reference)
//
#include <hip/hip_runtime.h>
#include <hip/hip_bf16.h>

// Problem constants (from reference): N=100000, F=128, E=640000, OUT=16
#define F_DIM 128
#define OUT_DIM 16

typedef _Float16 half8 __attribute__((ext_vector_type(8)));
typedef float floatx4 __attribute__((ext_vector_type(4)));
typedef unsigned short us8 __attribute__((ext_vector_type(8)));

// ---------------------------------------------------------------------------
// Kernel 0: build fp16 hi/lo B-fragments for mfma_f32_16x16x32_f16.
// B[k][n] layout: lane holds n = lane&15, k = (lane>>4)*8 + j.
// t=0: u-weights W[o][k], t=1: v-weights W[o][128+k]. 8 KB per term, L1-hot.
// (byte-identical to R4/R5/R6 — proven)
__global__ __launch_bounds__(256) void wprep_kernel(
    const float* __restrict__ W, _Float16* __restrict__ Bhi,
    _Float16* __restrict__ Blo)
{
    int tid = blockIdx.x * 256 + threadIdx.x;     // 0..4095
    if (tid >= 4096) return;
    int j    = tid & 7;
    int lane = (tid >> 3) & 63;
    int t    = (tid >> 9) & 1;
    int s    = (tid >> 10) & 3;
    int n = lane & 15;
    int q = lane >> 4;
    int k = s * 32 + q * 8 + j;
    float w = W[n * 256 + t * 128 + k];
    _Float16 hi = (_Float16)w;
    _Float16 lo = (_Float16)(w - (float)hi);
    Bhi[tid] = hi;
    Blo[tid] = lo;
}

// ---------------------------------------------------------------------------
// Kernel 1: PuF[n][o] = h[n].Wu + b ; PvF[n][o] = h[n].Wv   (fp32 tables)
// fp16-MFMA hi/lo split, fp32 accumulate. Epilogue is R4's proven scalar
// fp32 dword stores, only the destination split into two tables.
__global__ __launch_bounds__(256) void proj_mfma_kernel(
    const float* __restrict__ h, const _Float16* __restrict__ Bhi,
    const _Float16* __restrict__ Blo, const float* __restrict__ b,
    float* __restrict__ PuF, float* __restrict__ PvF, int N)
{
    const int lane = threadIdx.x & 63;
    const int wave = threadIdx.x >> 6;
    const int n = lane & 15;
    const int q = lane >> 4;
    const int row_base = blockIdx.x * 64 + wave * 16;
    if (row_base >= N) return;          // no LDS / barriers below: safe

    int arow = row_base + n;            // A-operand row this lane feeds
    if (arow >= N) arow = N - 1;        // clamped rows only affect unstored D rows
    const float* hrow = h + (size_t)arow * F_DIM + q * 8;

    floatx4 c0 = {0.f, 0.f, 0.f, 0.f};
    floatx4 c1 = {0.f, 0.f, 0.f, 0.f};

    #pragma unroll
    for (int s = 0; s < 4; ++s) {
        float av[8];
        *(float4*)(av)     = *(const float4*)(hrow + s * 32);
        *(float4*)(av + 4) = *(const float4*)(hrow + s * 32 + 4);
        half8 ah, al;
        #pragma unroll
        for (int j = 0; j < 8; ++j) {
            _Float16 hi = (_Float16)av[j];
            ah[j] = hi;
            al[j] = (_Float16)(av[j] - (float)hi);
        }
        const int base0 = (s * 2 + 0) * 512 + lane * 8;
        const int base1 = (s * 2 + 1) * 512 + lane * 8;
        half8 bh0 = *(const half8*)(Bhi + base0);
        half8 bl0 = *(const half8*)(Blo + base0);
        half8 bh1 = *(const half8*)(Bhi + base1);
        half8 bl1 = *(const half8*)(Blo + base1);

        c0 = __builtin_amdgcn_mfma_f32_16x16x32_f16(ah, bh0, c0, 0, 0, 0);
        c0 = __builtin_amdgcn_mfma_f32_16x16x32_f16(ah, bl0, c0, 0, 0, 0);
        c0 = __builtin_amdgcn_mfma_f32_16x16x32_f16(al, bh0, c0, 0, 0, 0);
        c1 = __builtin_amdgcn_mfma_f32_16x16x32_f16(ah, bh1, c1, 0, 0, 0);
        c1 = __builtin_amdgcn_mfma_f32_16x16x32_f16(ah, bl1, c1, 0, 0, 0);
        c1 = __builtin_amdgcn_mfma_f32_16x16x32_f16(al, bh1, c1, 0, 0, 0);
    }

    const float bn = b[n];
    #pragma unroll
    for (int reg = 0; reg < 4; ++reg) {
        int row = row_base + q * 4 + reg;
        if (row < N) {
            PuF[(size_t)row * 16 + n] = c0[reg] + bn;   // u half + bias
            PvF[(size_t)row * 16 + n] = c1[reg];        // v half
        }
    }
}

// ---------------------------------------------------------------------------
// Kernel 1b: pack fp32 tables -> bf16 dword-packed tables.
// One thread per OUTPUT DWORD: reads 2 adjacent fp32, RNE-rounds to bf16,
// writes one packed uint. No cross-lane ops, no sub-dword stores.
__device__ __forceinline__ unsigned bf16_bits_rne(float f) {
    unsigned u = __builtin_bit_cast(unsigned, f);
    unsigned rounding = 0x7FFFu + ((u >> 16) & 1u);
    return (u + rounding) >> 16;          // RNE; NaN not possible here
}

__global__ __launch_bounds__(256) void pack_kernel(
    const float* __restrict__ PuF, const float* __restrict__ PvF,
    unsigned int* __restrict__ Pu16, unsigned int* __restrict__ Pv16,
    int total_dwords)   // = N*8 per table
{
    int tid = blockIdx.x * 256 + threadIdx.x;
    if (tid >= 2 * total_dwords) return;
    const int isV = tid >= total_dwords;
    const int t = isV ? tid - total_dwords : tid;
    const float* S = isV ? PvF : PuF;
    unsigned lo = bf16_bits_rne(S[(size_t)t * 2]);
    unsigned hi = bf16_bits_rne(S[(size_t)t * 2 + 1]);
    unsigned packed = lo | (hi << 16);
    if (isV) Pv16[t] = packed;
    else     Pu16[t] = packed;
}

// ---------------------------------------------------------------------------
// Kernel 2: out[e][o] = Pu[src[e]][o] + Pv[dst[e]][o]   (bias already in Pu)
// R5's exact gather structure (passed first-check on HW): 2 lanes/edge, each
// loads 16B (8 bf16) per table, <<16 converts, adds, 32B contiguous NT store.
__global__ __launch_bounds__(256) void gather_kernel(
    const unsigned short* __restrict__ Pu, const unsigned short* __restrict__ Pv,
    const int* __restrict__ src, const int* __restrict__ dst,
    float* __restrict__ out, int E)
{
    const int tid = blockIdx.x * blockDim.x + threadIdx.x;
    const int e = tid >> 1;
    const int q = tid & 1;
    if (e >= E) return;
    const int s = src[e];
    const int d = dst[e];
    const us8 pu = *(const us8*)(Pu + (size_t)s * 16 + q * 8);
    const us8 pv = *(const us8*)(Pv + (size_t)d * 16 + q * 8);
    floatx4 r0, r1;
    #pragma unroll
    for (int j = 0; j < 4; ++j) {
        r0[j] = __uint_as_float((unsigned)pu[j] << 16)
              + __uint_as_float((unsigned)pv[j] << 16);
        r1[j] = __uint_as_float((unsigned)pu[j + 4] << 16)
              + __uint_as_float((unsigned)pv[j + 4] << 16);
    }
    floatx4* o = (floatx4*)out + (size_t)tid * 2;
    __builtin_nontemporal_store(r0, o);
    __builtin_nontemporal_store(r1, o + 1);
}

// Fallback (only if workspace too small): direct per-(edge,out) dot, fp32.
__global__ __launch_bounds__(256) void direct_kernel(
    const float* __restrict__ h, const int* __restrict__ src,
    const int* __restrict__ dst, const float* __restrict__ W,
    const float* __restrict__ b, float* __restrict__ out, int E)
{
    const int tid = blockIdx.x * blockDim.x + threadIdx.x;
    if (tid >= E * OUT_DIM) return;
    const int e = tid >> 4;
    const int o = tid & 15;
    const float* hu = h + (size_t)src[e] * F_DIM;
    const float* hv = h + (size_t)dst[e] * F_DIM;
    const float* wu = W + (size_t)o * 256;
    const float* wv = wu + 128;
    float acc = b[o];
    for (int k = 0; k < 128; ++k) acc = fmaf(hu[k], wu[k], acc);
    for (int k = 0; k < 128; ++k) acc = fmaf(hv[k], wv[k], acc);
    out[tid] = acc;
}

extern "C" void kernel_launch(void* const* d_in, const int* in_sizes, int n_in,
                              void* d_out, int out_size, void* d_ws, size_t ws_size,
                              hipStream_t stream) {
    const float* h   = (const float*)d_in[0];
    const int*   src = (const int*)d_in[1];
    const int*   dst = (const int*)d_in[2];
    const float* W   = (const float*)d_in[3];
    const float* b   = (const float*)d_in[4];
    float* out = (float*)d_out;

    const int N = in_sizes[0] / F_DIM;     // 100000
    const int E = in_sizes[1];             // 640000

    const size_t pf_bytes  = (size_t)N * 16 * sizeof(float);      // 6.4 MB
    const size_t pf_al     = (pf_bytes + 255) & ~(size_t)255;
    const size_t p16_bytes = (size_t)N * 8 * sizeof(unsigned);    // 3.2 MB
    const size_t p16_al    = (p16_bytes + 255) & ~(size_t)255;
    const size_t bf_bytes  = 4096 * sizeof(_Float16);             // 8 KB each

    if (ws_size >= 2 * pf_al + 2 * p16_al + 2 * bf_bytes) {
        float*        PuF  = (float*)d_ws;
        float*        PvF  = (float*)((char*)d_ws + pf_al);
        unsigned int* Pu16 = (unsigned int*)((char*)d_ws + 2 * pf_al);
        unsigned int* Pv16 = (unsigned int*)((char*)d_ws + 2 * pf_al + p16_al);
        _Float16*     Bhi  = (_Float16*)((char*)d_ws + 2 * pf_al + 2 * p16_al);
        _Float16*     Blo  = Bhi + 4096;

        wprep_kernel<<<16, 256, 0, stream>>>(W, Bhi, Blo);

        const int blocks1 = (N + 63) / 64;
        proj_mfma_kernel<<<blocks1, 256, 0, stream>>>(h, Bhi, Blo, b, PuF, PvF, N);

        const int total_dw = N * 8;
        const int blocksP  = (2 * total_dw + 255) / 256;
        pack_kernel<<<blocksP, 256, 0, stream>>>(PuF, PvF, Pu16, Pv16, total_dw);

        const int total2  = E * 2;
        const int blocks2 = (total2 + 255) / 256;
        gather_kernel<<<blocks2, 256, 0, stream>>>(
            (const unsigned short*)Pu16, (const unsigned short*)Pv16,
            src, dst, out, E);
    } else {
        const int total  = E * OUT_DIM;
        const int blocks = (total + 255) / 256;
        direct_kernel<<<blocks, 256, 0, stream>>>(h, src, dst, W, b, out, E);
    }
}

// Round 8
// 125.500 us; speedup vs baseline: 1.0559x; 1.0559x over previous
//
#include <hip/hip_runtime.h>
#include <hip/hip_bf16.h>

// Problem constants (from reference): N=100000, F=128, E=640000, OUT=16
#define F_DIM 128
#define OUT_DIM 16

typedef _Float16 half8 __attribute__((ext_vector_type(8)));
typedef float floatx4 __attribute__((ext_vector_type(4)));
typedef unsigned short us8 __attribute__((ext_vector_type(8)));

// ---------------------------------------------------------------------------
// Kernel 0: build fp16 hi/lo weight fragments (k = quad*8+j, lane&15 = o).
// Used as the A operand of the transposed MFMA (identical lane mapping to the
// B-operand use in R4-R7, both HW-proven). 8 KB per term, L1-hot.
__global__ __launch_bounds__(256) void wprep_kernel(
    const float* __restrict__ W, _Float16* __restrict__ Bhi,
    _Float16* __restrict__ Blo)
{
    int tid = blockIdx.x * 256 + threadIdx.x;     // 0..4095
    if (tid >= 4096) return;
    int j    = tid & 7;
    int lane = (tid >> 3) & 63;
    int t    = (tid >> 9) & 1;
    int s    = (tid >> 10) & 3;
    int n = lane & 15;
    int q = lane >> 4;
    int k = s * 32 + q * 8 + j;
    float w = W[n * 256 + t * 128 + k];
    _Float16 hi = (_Float16)w;
    _Float16 lo = (_Float16)(w - (float)hi);
    Bhi[tid] = hi;
    Blo[tid] = lo;
}

__device__ __forceinline__ unsigned bf16_bits_rne(float f) {
    unsigned u = __builtin_bit_cast(unsigned, f);
    unsigned rounding = 0x7FFFu + ((u >> 16) & 1u);
    return (u + rounding) >> 16;          // RNE; NaN not possible here
}

// ---------------------------------------------------------------------------
// Kernel 1: Pu16[node][o] = bf16(h[node].Wu + b) ; Pv16 likewise (no bias).
// TRANSPOSED MFMA: D[m=o][n=node] = sum_k W'[o][k] * h[node][k]
//   A = weight frag (lane&15 -> o, quad*8+j -> k)   [wprep table]
//   B = h frag      (lane&15 -> node, quad*8+j -> k) [same loads as R4-R7]
//   D: row = quad*4+reg = o, col = lane&15 = node
// => each lane holds o = 4q..4q+3 for ONE node: pack pairs into dwords
//    in-register (no shfl), store dword-only. fp32 accumulate, one RNE round.
__global__ __launch_bounds__(256) void proj_mfma_kernel(
    const float* __restrict__ h, const _Float16* __restrict__ Bhi,
    const _Float16* __restrict__ Blo, const float* __restrict__ b,
    unsigned int* __restrict__ Pu16, unsigned int* __restrict__ Pv16, int N)
{
    const int lane = threadIdx.x & 63;
    const int wave = threadIdx.x >> 6;
    const int n = lane & 15;            // node within tile
    const int q = lane >> 4;            // quad: o-group and k-group selector
    const int row_base = blockIdx.x * 64 + wave * 16;
    if (row_base >= N) return;          // whole wave exits; no barriers below

    int arow = row_base + n;            // h row this lane feeds (B operand)
    if (arow >= N) arow = N - 1;        // clamped rows -> unstored D columns
    const float* hrow = h + (size_t)arow * F_DIM + q * 8;

    floatx4 c0 = {0.f, 0.f, 0.f, 0.f};   // u half: D[o][node]
    floatx4 c1 = {0.f, 0.f, 0.f, 0.f};   // v half

    #pragma unroll
    for (int s = 0; s < 4; ++s) {
        float av[8];
        *(float4*)(av)     = *(const float4*)(hrow + s * 32);
        *(float4*)(av + 4) = *(const float4*)(hrow + s * 32 + 4);
        half8 ah, al;
        #pragma unroll
        for (int j = 0; j < 8; ++j) {
            _Float16 hi = (_Float16)av[j];
            ah[j] = hi;
            al[j] = (_Float16)(av[j] - (float)hi);
        }
        const int base0 = (s * 2 + 0) * 512 + lane * 8;
        const int base1 = (s * 2 + 1) * 512 + lane * 8;
        half8 wh0 = *(const half8*)(Bhi + base0);
        half8 wl0 = *(const half8*)(Blo + base0);
        half8 wh1 = *(const half8*)(Bhi + base1);
        half8 wl1 = *(const half8*)(Blo + base1);

        // D += A(W) * B(h): weight hi/lo split against h hi/lo split
        c0 = __builtin_amdgcn_mfma_f32_16x16x32_f16(wh0, ah, c0, 0, 0, 0);
        c0 = __builtin_amdgcn_mfma_f32_16x16x32_f16(wl0, ah, c0, 0, 0, 0);
        c0 = __builtin_amdgcn_mfma_f32_16x16x32_f16(wh0, al, c0, 0, 0, 0);
        c1 = __builtin_amdgcn_mfma_f32_16x16x32_f16(wh1, ah, c1, 0, 0, 0);
        c1 = __builtin_amdgcn_mfma_f32_16x16x32_f16(wl1, ah, c1, 0, 0, 0);
        c1 = __builtin_amdgcn_mfma_f32_16x16x32_f16(wh1, al, c1, 0, 0, 0);
    }

    const int node = row_base + n;      // D column this lane owns
    if (node < N) {
        const floatx4 bv = *(const floatx4*)(b + 4 * q);   // b[4q+reg]
        unsigned u0 = bf16_bits_rne(c0[0] + bv[0]) | (bf16_bits_rne(c0[1] + bv[1]) << 16);
        unsigned u1 = bf16_bits_rne(c0[2] + bv[2]) | (bf16_bits_rne(c0[3] + bv[3]) << 16);
        unsigned v0 = bf16_bits_rne(c1[0]) | (bf16_bits_rne(c1[1]) << 16);
        unsigned v1 = bf16_bits_rne(c1[2]) | (bf16_bits_rne(c1[3]) << 16);
        const size_t base = (size_t)node * 8 + 2 * q;
        Pu16[base]     = u0;
        Pu16[base + 1] = u1;
        Pv16[base]     = v0;
        Pv16[base + 1] = v1;
    }
}

// ---------------------------------------------------------------------------
// Kernel 2: out[e][o] = Pu[src[e]][o] + Pv[dst[e]][o]   (bias already in Pu)
// Byte-identical to R7's passing gather: 2 lanes/edge, 16B bf16 loads per
// table, <<16 converts, 32B contiguous NT stores.
__global__ __launch_bounds__(256) void gather_kernel(
    const unsigned short* __restrict__ Pu, const unsigned short* __restrict__ Pv,
    const int* __restrict__ src, const int* __restrict__ dst,
    float* __restrict__ out, int E)
{
    const int tid = blockIdx.x * blockDim.x + threadIdx.x;
    const int e = tid >> 1;
    const int q = tid & 1;
    if (e >= E) return;
    const int s = src[e];
    const int d = dst[e];
    const us8 pu = *(const us8*)(Pu + (size_t)s * 16 + q * 8);
    const us8 pv = *(const us8*)(Pv + (size_t)d * 16 + q * 8);
    floatx4 r0, r1;
    #pragma unroll
    for (int j = 0; j < 4; ++j) {
        r0[j] = __uint_as_float((unsigned)pu[j] << 16)
              + __uint_as_float((unsigned)pv[j] << 16);
        r1[j] = __uint_as_float((unsigned)pu[j + 4] << 16)
              + __uint_as_float((unsigned)pv[j + 4] << 16);
    }
    floatx4* o = (floatx4*)out + (size_t)tid * 2;
    __builtin_nontemporal_store(r0, o);
    __builtin_nontemporal_store(r1, o + 1);
}

// Fallback (only if workspace too small): direct per-(edge,out) dot, fp32.
__global__ __launch_bounds__(256) void direct_kernel(
    const float* __restrict__ h, const int* __restrict__ src,
    const int* __restrict__ dst, const float* __restrict__ W,
    const float* __restrict__ b, float* __restrict__ out, int E)
{
    const int tid = blockIdx.x * blockDim.x + threadIdx.x;
    if (tid >= E * OUT_DIM) return;
    const int e = tid >> 4;
    const int o = tid & 15;
    const float* hu = h + (size_t)src[e] * F_DIM;
    const float* hv = h + (size_t)dst[e] * F_DIM;
    const float* wu = W + (size_t)o * 256;
    const float* wv = wu + 128;
    float acc = b[o];
    for (int k = 0; k < 128; ++k) acc = fmaf(hu[k], wu[k], acc);
    for (int k = 0; k < 128; ++k) acc = fmaf(hv[k], wv[k], acc);
    out[tid] = acc;
}

extern "C" void kernel_launch(void* const* d_in, const int* in_sizes, int n_in,
                              void* d_out, int out_size, void* d_ws, size_t ws_size,
                              hipStream_t stream) {
    const float* h   = (const float*)d_in[0];
    const int*   src = (const int*)d_in[1];
    const int*   dst = (const int*)d_in[2];
    const float* W   = (const float*)d_in[3];
    const float* b   = (const float*)d_in[4];
    float* out = (float*)d_out;

    const int N = in_sizes[0] / F_DIM;     // 100000
    const int E = in_sizes[1];             // 640000

    const size_t p16_bytes = (size_t)N * 8 * sizeof(unsigned);    // 3.2 MB
    const size_t p16_al    = (p16_bytes + 255) & ~(size_t)255;
    const size_t bf_bytes  = 4096 * sizeof(_Float16);             // 8 KB each

    if (ws_size >= 2 * p16_al + 2 * bf_bytes) {
        unsigned int* Pu16 = (unsigned int*)d_ws;
        unsigned int* Pv16 = (unsigned int*)((char*)d_ws + p16_al);
        _Float16*     Bhi  = (_Float16*)((char*)d_ws + 2 * p16_al);
        _Float16*     Blo  = Bhi + 4096;

        wprep_kernel<<<16, 256, 0, stream>>>(W, Bhi, Blo);

        const int blocks1 = (N + 63) / 64;
        proj_mfma_kernel<<<blocks1, 256, 0, stream>>>(h, Bhi, Blo, b, Pu16, Pv16, N);

        const int total2  = E * 2;
        const int blocks2 = (total2 + 255) / 256;
        gather_kernel<<<blocks2, 256, 0, stream>>>(
            (const unsigned short*)Pu16, (const unsigned short*)Pv16,
            src, dst, out, E);
    } else {
        const int total  = E * OUT_DIM;
        const int blocks = (total + 255) / 256;
        direct_kernel<<<blocks, 256, 0, stream>>>(h, src, dst, W, b, out, E);
    }
}